// Round 18
// baseline (457.209 us; speedup 1.0000x reference)
//
#include <hip/hip_runtime.h>
#include <stdint.h>

// ---------- types / helpers ----------
typedef short bf16x8 __attribute__((ext_vector_type(8)));
typedef float f32x4 __attribute__((ext_vector_type(4)));

__device__ inline float bf2f(uint16_t u){ uint32_t v = ((uint32_t)u)<<16; float f; __builtin_memcpy(&f,&v,4); return f; }
__device__ inline float ubf(uint32_t u){ float f; __builtin_memcpy(&f,&u,4); return f; }
__device__ inline uint16_t f2bf(float f){ uint32_t u; __builtin_memcpy(&u,&f,4); u += 0x7fffu + ((u>>16)&1u); return (uint16_t)(u>>16); }
// round-half-up bf16 (2 ops), for P-pack only
__device__ inline uint16_t f2bfr(float f){ uint32_t u; __builtin_memcpy(&u,&f,4); return (uint16_t)((u + 0x8000u)>>16); }

#define CCH   192
#define HH    128
#define WWD   128
#define HWSZ  16384      // 128*128
#define NPOS_SIDE 32768  // 2*16384
#define NPOS  65536
#define NKT   576
#define SCALE_F 0.17677669529663687f
#define SCALE2_F 0.2550348727f      // SCALE * log2(e)

// ---------- kernel 1: convert weights fp32->bf16 ----------
__global__ __launch_bounds__(256) void k_cvtw(const float* qkvw, const float* l1, const float* r1,
        const float* l2, const float* r2,
        uint16_t* wq, uint16_t* w1l, uint16_t* w1r, uint16_t* w2l, uint16_t* w2r){
    int which = blockIdx.y;
    int i = blockIdx.x*256 + threadIdx.x;
    const float* src; uint16_t* dst; int n;
    switch(which){
      case 0: src=qkvw; dst=wq;  n=576*192; break;
      case 1: src=l1;   dst=w1l; n=192*192; break;
      case 2: src=r1;   dst=w1r; n=192*192; break;
      case 3: src=l2;   dst=w2l; n=192*192; break;
      default:src=r2;   dst=w2r; n=192*192; break;
    }
    if(i<n) dst[i] = f2bf(src[i]);
}

// ---------- kernel 2: rel-pos bias, COALESCED lane-matched layout, pre-scaled log2(e) ----------
// biasQ[h][cg(18)][qb(16)][half(2)][lg(4)][lr(16)] : uint2 = 4 bf16 for
//   q = qb*16 + lr, kt = cg*32 + half*16 + lg*4 + r
__global__ __launch_bounds__(256) void k_bias(const float* rpb, uint2* biasQ){
    int e = blockIdx.x*256 + threadIdx.x;
    if(e >= 6*18*16*2*4*16) return;   // 221184
    int lr   = e & 15;
    int lg   = (e >> 4) & 3;
    int half = (e >> 6) & 1;
    int qb   = (e >> 7) & 15;
    int hc   = e >> 11;
    int c    = hc % 18;
    int h    = hc / 18;
    int q = qb*16 + lr;
    int qi = q >> 4, qj = q & 15;
    uint32_t w0 = 0, w1 = 0;
    #pragma unroll
    for(int r=0;r<4;r++){
        int kt = c*32 + half*16 + lg*4 + r;
        int ki = kt/24, kj = kt%24;
        int id = (ki - qi - 7)*39 + (kj - qj - 7);
        id %= 1521; if(id < 0) id += 1521;
        uint32_t bv = f2bf(rpb[id*6 + h] * 1.4426950408889634f);
        if(r < 2) w0 |= bv << (16*r); else w1 |= bv << (16*(r-2));
    }
    biasQ[e] = make_uint2(w0, w1);
}

// ---------- kernel 3: LN over C, single-read LDS-tiled (64 pos x 192 c) ----------
#define LNP 65
__global__ __launch_bounds__(256) void k_ln1(const float* xl, const float* xr,
        const float* gl, const float* bl, const float* gr, const float* br,
        uint16_t* nlr_bf){
    __shared__ float L[192*LNP];       // 49920 B
    __shared__ float redA[4][64];
    __shared__ float redB[4][64];
    __shared__ float mrs[2][64];
    int pos0 = blockIdx.x * 64;        // 1024 blocks
    int s   = pos0 >> 15;
    int loc = pos0 & 32767;
    const float* x = s ? xr : xl;
    const float* g = s ? gr : gl;
    const float* b = s ? br : bl;
    int bb = loc >> 14, hw0 = loc & 16383;
    const float* xp = x + (size_t)bb*CCH*HWSZ + hw0;
    int tid = threadIdx.x;
    {   // load tile (coalesced 256B rows)
        int p = tid & 63, cq = tid >> 6;
        for(int c = cq; c < 192; c += 4)
            L[c*LNP + p] = xp[(size_t)c*HWSZ + p];
    }
    __syncthreads();
    {   // partial sums: 4 threads per position over c-quarters
        int p = tid & 63, part = tid >> 6;
        float sum = 0.f, sq = 0.f;
        for(int c = part*48; c < part*48+48; c++){
            float v = L[c*LNP + p];
            sum += v; sq += v*v;
        }
        redA[part][p] = sum; redB[part][p] = sq;
    }
    __syncthreads();
    if(tid < 64){
        int p = tid;
        float sum = redA[0][p]+redA[1][p]+redA[2][p]+redA[3][p];
        float sq  = redB[0][p]+redB[1][p]+redB[2][p]+redB[3][p];
        float mean = sum*(1.f/192.f);
        float var  = sq*(1.f/192.f) - mean*mean;
        mrs[0][p] = mean;
        mrs[1][p] = rsqrtf(var + 1e-6f);
    }
    __syncthreads();
    {   // output: 4 threads per position, 48 c each as 6 x 16B stores
        int p = tid >> 2, tp = tid & 3;
        float mean = mrs[0][p], rstd = mrs[1][p];
        uint16_t* obp = nlr_bf + (size_t)(pos0 + p)*CCH + tp*48;
        for(int cb = 0; cb < 6; cb++){
            alignas(16) uint16_t tmp[8];
            #pragma unroll
            for(int k=0;k<8;k++){
                int c = tp*48 + cb*8 + k;
                float y = (L[c*LNP + p]-mean)*rstd*g[c] + b[c];
                tmp[k] = f2bf(y);
            }
            *(uint4*)(obp + cb*8) = *(const uint4*)tmp;
        }
    }
}

// ---------- kernel 4a: merged 192x192 conv GEMMs (z selects which of 4) ----------
__global__ __launch_bounds__(256) void k_gemm4(const uint16_t* __restrict__ x2,
        const uint16_t* __restrict__ nlr_bf,
        const uint16_t* __restrict__ w1l, const uint16_t* __restrict__ w1r,
        const uint16_t* __restrict__ w2l, const uint16_t* __restrict__ w2r,
        const float* __restrict__ lp1b, const float* __restrict__ rp1b,
        const float* __restrict__ lp2b, const float* __restrict__ rp2b,
        uint16_t* __restrict__ QLb, uint16_t* __restrict__ QRb,
        uint16_t* __restrict__ VLb, uint16_t* __restrict__ VRb){
    const int K = 192, N = 192;
    int z = blockIdx.z;
    const uint16_t* A; const uint16_t* W; const float* bias; uint16_t* out;
    switch(z){
      case 0: A = x2;                          W = w1l; bias = lp1b; out = QLb; break;
      case 1: A = x2 + (size_t)32768*192;      W = w1r; bias = rp1b; out = QRb; break;
      case 2: A = nlr_bf;                      W = w2l; bias = lp2b; out = VLb; break;
      default:A = nlr_bf + (size_t)32768*192;  W = w2r; bias = rp2b; out = VRb; break;
    }
    int tid = threadIdx.x;
    int w = tid >> 6, lane = tid & 63;
    int lr = lane & 15, lg = lane >> 4;
    int row0 = blockIdx.y*128 + w*16;
    int col0 = blockIdx.x*64;
    const uint16_t* Ap0 = A + (size_t)(row0 + lr)*K + lg*8;
    const uint16_t* Ap1 = Ap0 + (size_t)64*K;
    const uint16_t* Wp = W + (size_t)col0*K + lg*8;
    f32x4 acc[2][4] = {};
    for(int kk=0; kk<6; kk++){
        bf16x8 a0 = *(const bf16x8*)(Ap0 + kk*32);
        bf16x8 a1 = *(const bf16x8*)(Ap1 + kk*32);
        #pragma unroll
        for(int nf=0; nf<4; nf++){
            bf16x8 bfr = *(const bf16x8*)(Wp + (size_t)(nf*16 + lr)*K + kk*32);
            acc[0][nf] = __builtin_amdgcn_mfma_f32_16x16x32_bf16(a0, bfr, acc[0][nf], 0,0,0);
            acc[1][nf] = __builtin_amdgcn_mfma_f32_16x16x32_bf16(a1, bfr, acc[1][nf], 0,0,0);
        }
    }
    #pragma unroll
    for(int nf=0; nf<4; nf++){
        int col = col0 + nf*16 + lr;
        float bv = bias[col];
        #pragma unroll
        for(int m=0; m<2; m++){
            #pragma unroll
            for(int r=0;r<4;r++){
                int row = row0 + m*64 + lg*4 + r;
                out[(size_t)row*N + col] = f2bf(acc[m][nf][r] + bv);
            }
        }
    }
}

// ---------- kernel 4b: GEMM (192-col tiles) for the qkv projection ----------
__global__ __launch_bounds__(256) void k_gemmw(const uint16_t* __restrict__ A,
        const uint16_t* __restrict__ W, const float* __restrict__ bias,
        uint16_t* __restrict__ out, int K, int N){
    int tid = threadIdx.x;
    int w = tid >> 6, lane = tid & 63;
    int lr = lane & 15, lg = lane >> 4;
    int row0 = blockIdx.y*128 + w*16;
    int col0 = blockIdx.x*192;
    const uint16_t* Ap0 = A + (size_t)(row0 + lr)*K + lg*8;
    const uint16_t* Ap1 = Ap0 + (size_t)64*K;
    const uint16_t* Wp = W + (size_t)col0*K + lg*8;
    f32x4 acc[2][12] = {};
    int ksteps = K >> 5;
    for(int kk=0; kk<ksteps; kk++){
        bf16x8 a0 = *(const bf16x8*)(Ap0 + kk*32);
        bf16x8 a1 = *(const bf16x8*)(Ap1 + kk*32);
        #pragma unroll
        for(int nf=0; nf<12; nf++){
            bf16x8 bfr = *(const bf16x8*)(Wp + (size_t)(nf*16 + lr)*K + kk*32);
            acc[0][nf] = __builtin_amdgcn_mfma_f32_16x16x32_bf16(a0, bfr, acc[0][nf], 0,0,0);
            acc[1][nf] = __builtin_amdgcn_mfma_f32_16x16x32_bf16(a1, bfr, acc[1][nf], 0,0,0);
        }
    }
    #pragma unroll
    for(int nf=0; nf<12; nf++){
        int col = col0 + nf*16 + lr;
        float bv = bias[col];
        #pragma unroll
        for(int m=0; m<2; m++){
            #pragma unroll
            for(int r=0;r<4;r++){
                int row = row0 + m*64 + lg*4 + r;
                out[(size_t)row*N + col] = f2bf(acc[m][nf][r] + bv);
            }
        }
    }
}

// ---------- kernel 5: overlapping-window attention (swapped QK^T, lane-local P) ----------
// 256 thr = 4 waves, each wave 64 q-rows. 3 stages of 192 kt. (R13/R14-proven form,
// bias reads now coalesced via the new layout)
#define KPAD 40
#define STG  192
#define VTP  200
__global__ __launch_bounds__(256) void k_attn(const uint16_t* __restrict__ qkv,
        const uint2* __restrict__ biasQ, uint16_t* __restrict__ attout){
    __shared__ uint16_t Ks[STG*KPAD];      // 15360 B
    __shared__ uint16_t Vt[32*VTP];        // 12800 B  [d][kt-slot-permuted]

    int bid = blockIdx.x;                  // 1536
    int s = bid / 768; int r1 = bid % 768;
    int b = r1 / 384;  int r2 = r1 % 384;
    int head = r2 / 64; int win = r2 % 64;
    int hb = win >> 3, wb = win & 7;
    int tid = threadIdx.x;
    int posbase = s*NPOS_SIDE + b*HWSZ;

    int wv = tid >> 6, lane = tid & 63;
    int lr = lane & 15, lg = lane >> 4;

    bf16x8 qB[4];
    #pragma unroll
    for(int f=0; f<4; f++){
        int t = wv*64 + f*16 + lr;
        int pos = posbase + (hb*16 + (t>>4))*WWD + (wb*16 + (t&15));
        qB[f] = *(const bf16x8*)(qkv + (size_t)pos*NKT + head*32 + lg*8);
    }

    f32x4 acc[4][2] = {};
    float psum[4] = {0.f, 0.f, 0.f, 0.f};

    const uint16_t* kvbase = qkv + (size_t)posbase*NKT;
    const uint2* biasH = biasQ + (size_t)head*36864;   // 18*16*128

    for(int stg=0; stg<3; stg++){
        __syncthreads();
        for(int idx = tid; idx < STG*4; idx += 256){
            int ktl = idx >> 2, part = idx & 3;
            int ktg = stg*STG + ktl;
            int i = ktg/24, j = ktg%24;
            int h = hb*16 + i - 4, wv2 = wb*16 + j - 4;
            uint4 kd = {0,0,0,0}, vd = {0,0,0,0};
            if((unsigned)h < 128u && (unsigned)wv2 < 128u){
                const uint16_t* p = kvbase + (size_t)(h*WWD + wv2)*NKT + 192 + head*32 + part*8;
                kd = *(const uint4*)p;
                vd = *(const uint4*)(p + 192);
            }
            *(uint4*)(Ks + ktl*KPAD + part*8) = kd;
            int t32 = ktl & 31;
            int ktp = (ktl & ~31) + (((t32&12)<<1) + ((t32>>4)<<2) + (t32&3));
            const uint16_t* vs = (const uint16_t*)&vd;
            #pragma unroll
            for(int k2=0;k2<8;k2++) Vt[(part*8+k2)*VTP + ktp] = vs[k2];
        }
        __syncthreads();

        for(int kc=0; kc<6; kc++){
            int kt0 = kc*32;
            int cg  = stg*6 + kc;
            bf16x8 k0 = *(const bf16x8*)(Ks + (kt0 + lr)*KPAD + lg*8);
            bf16x8 k1 = *(const bf16x8*)(Ks + (kt0 + 16 + lr)*KPAD + lg*8);
            bf16x8 vb0 = *(const bf16x8*)(Vt + lr*VTP        + kt0 + lg*8);
            bf16x8 vb1 = *(const bf16x8*)(Vt + (16+lr)*VTP   + kt0 + lg*8);

            #pragma unroll
            for(int f=0; f<4; f++){
                f32x4 z = {0.f,0.f,0.f,0.f};
                f32x4 s0 = __builtin_amdgcn_mfma_f32_16x16x32_bf16(k0, qB[f], z, 0,0,0);
                f32x4 s1 = __builtin_amdgcn_mfma_f32_16x16x32_bf16(k1, qB[f], z, 0,0,0);
                int qb = wv*4 + f;
                const uint2* bq = biasH + ((size_t)cg*16 + qb)*128;
                uint2 bh0 = bq[lg*16 + lr];        // half 0, coalesced 512B/wave
                uint2 bh1 = bq[64 + lg*16 + lr];   // half 1
                float e0 = exp2f(__builtin_fmaf(s0[0], SCALE2_F, ubf(bh0.x << 16)));
                float e1 = exp2f(__builtin_fmaf(s0[1], SCALE2_F, ubf(bh0.x & 0xffff0000u)));
                float e2 = exp2f(__builtin_fmaf(s0[2], SCALE2_F, ubf(bh0.y << 16)));
                float e3 = exp2f(__builtin_fmaf(s0[3], SCALE2_F, ubf(bh0.y & 0xffff0000u)));
                float e4 = exp2f(__builtin_fmaf(s1[0], SCALE2_F, ubf(bh1.x << 16)));
                float e5 = exp2f(__builtin_fmaf(s1[1], SCALE2_F, ubf(bh1.x & 0xffff0000u)));
                float e6 = exp2f(__builtin_fmaf(s1[2], SCALE2_F, ubf(bh1.y << 16)));
                float e7 = exp2f(__builtin_fmaf(s1[3], SCALE2_F, ubf(bh1.y & 0xffff0000u)));
                psum[f] += ((e0+e1)+(e2+e3)) + ((e4+e5)+(e6+e7));
                bf16x8 pv;
                pv[0] = (short)f2bfr(e0); pv[1] = (short)f2bfr(e1);
                pv[2] = (short)f2bfr(e2); pv[3] = (short)f2bfr(e3);
                pv[4] = (short)f2bfr(e4); pv[5] = (short)f2bfr(e5);
                pv[6] = (short)f2bfr(e6); pv[7] = (short)f2bfr(e7);
                acc[f][0] = __builtin_amdgcn_mfma_f32_16x16x32_bf16(pv, vb0, acc[f][0], 0,0,0);
                acc[f][1] = __builtin_amdgcn_mfma_f32_16x16x32_bf16(pv, vb1, acc[f][1], 0,0,0);
            }
        }
    }

    #pragma unroll
    for(int f=0; f<4; f++){
        float dsum = psum[f];
        dsum += __shfl_xor(dsum, 16);
        dsum += __shfl_xor(dsum, 32);
        float invl = 1.f / dsum;
        #pragma unroll
        for(int r=0;r<4;r++){
            float inv = __shfl(invl, 4*lg + r);
            int q = wv*64 + f*16 + 4*lg + r;
            int pos = posbase + (hb*16 + (q>>4))*WWD + (wb*16 + (q&15));
            #pragma unroll
            for(int n=0;n<2;n++){
                attout[(size_t)pos*CCH + head*32 + n*16 + lr] = f2bf(acc[f][n][r]*inv);
            }
        }
    }
}

// ---------- kernel 6: LN over C of attention output (bf16 rows) -> bf16 rows ----------
__global__ __launch_bounds__(256) void k_ln2(const uint16_t* __restrict__ attout,
        const float* gl, const float* bl, const float* gr, const float* br,
        uint16_t* __restrict__ x2){
    int wv = threadIdx.x >> 6, lane = threadIdx.x & 63;
    int pos = blockIdx.x*4 + wv;
    int s = pos >> 15;
    const float* g = s ? gr : gl;
    const float* b = s ? br : bl;
    const uint16_t* ip = attout + (size_t)pos*CCH;
    float v[3]; float sum=0.f, sq=0.f;
    #pragma unroll
    for(int k=0;k<3;k++){ v[k] = bf2f(ip[lane + 64*k]); sum += v[k]; sq += v[k]*v[k]; }
    #pragma unroll
    for(int m=1;m<64;m<<=1){ sum += __shfl_xor(sum,m); sq += __shfl_xor(sq,m); }
    float mean = sum*(1.f/192.f);
    float var  = sq*(1.f/192.f) - mean*mean;
    float rstd = rsqrtf(var + 1e-6f);
    uint16_t* op = x2 + (size_t)pos*CCH;
    #pragma unroll
    for(int k=0;k<3;k++){
        int c = lane + 64*k;
        op[c] = f2bf((v[k]-mean)*rstd*g[c] + b[c]);
    }
}

// ---------- kernel 7: cross-att scores + both softmaxes; block per (b, x=w), 512 thr ----------
__global__ __launch_bounds__(512) void k_cross1(const uint16_t* __restrict__ QL,
        const uint16_t* __restrict__ QR, uint16_t* __restrict__ Prow, uint16_t* __restrict__ PcolT){
    __shared__ float S[128*128];  // 64 KB
    __shared__ float cred[4][128];
    __shared__ float colm[128];
    __shared__ float colinv[128];
    int bid = blockIdx.x; int b = bid >> 7, x = bid & 127;
    int tid = threadIdx.x;
    int wv = tid>>6, lane = tid&63, lr = lane&15, lg = lane>>4;   // wv 0..7
    const uint16_t* Abase = QL + (size_t)b*HWSZ*CCH;
    const uint16_t* Bbase = QR + (size_t)b*HWSZ*CCH;
    f32x4 acc[8] = {};
    for(int kk=0; kk<6; kk++){
        int i = wv*16 + lr;
        bf16x8 af = *(const bf16x8*)(Abase + (size_t)(i*WWD + x)*CCH + kk*32 + lg*8);
        #pragma unroll
        for(int nf=0; nf<8; nf++){
            int j = nf*16 + lr;
            bf16x8 bfr = *(const bf16x8*)(Bbase + (size_t)(j*WWD + x)*CCH + kk*32 + lg*8);
            acc[nf] = __builtin_amdgcn_mfma_f32_16x16x32_bf16(af, bfr, acc[nf], 0,0,0);
        }
    }
    #pragma unroll
    for(int nf=0;nf<8;nf++)
    #pragma unroll
    for(int r=0;r<4;r++){
        int i = wv*16 + lg*4 + r; int j = nf*16 + lr;
        S[i*128 + j] = acc[nf][r]*SCALE_F;
    }
    __syncthreads();
    uint16_t* prb = Prow + (size_t)(b*128 + x)*128*128;
    for(int i = wv*16; i < wv*16+16; i++){
        float v0 = S[i*128 + lane], v1 = S[i*128 + 64 + lane];
        float m = fmaxf(v0,v1);
        #pragma unroll
        for(int k=1;k<64;k<<=1) m = fmaxf(m, __shfl_xor(m,k));
        float e0 = __expf(v0-m), e1 = __expf(v1-m);
        float ss = e0+e1;
        #pragma unroll
        for(int k=1;k<64;k<<=1) ss += __shfl_xor(ss,k);
        float inv = 1.f/ss;
        prb[i*128 + lane]      = f2bf(e0*inv);
        prb[i*128 + 64 + lane] = f2bf(e1*inv);
    }
    int j = tid & 127, q4 = tid >> 7;
    int i0 = q4*32;
    float m = -1e30f;
    for(int i=i0; i<i0+32; i++) m = fmaxf(m, S[i*128 + j]);
    cred[q4][j] = m;
    __syncthreads();
    if(tid < 128) colm[tid] = fmaxf(fmaxf(cred[0][tid], cred[1][tid]), fmaxf(cred[2][tid], cred[3][tid]));
    __syncthreads();
    float mj = colm[j];
    float ssum = 0.f;
    for(int i=i0; i<i0+32; i++) ssum += __expf(S[i*128 + j] - mj);
    cred[q4][j] = ssum;
    __syncthreads();
    if(tid < 128) colinv[tid] = 1.f/(cred[0][tid] + cred[1][tid] + cred[2][tid] + cred[3][tid]);
    __syncthreads();
    float cinv = colinv[j];
    uint16_t* pcb = PcolT + (size_t)(b*128 + x)*128*128;
    for(int i=i0; i<i0+32; i++) pcb[j*128 + i] = f2bf(__expf(S[i*128 + j] - mj)*cinv);
}

// ---------- kernel 8: PV GEMMs + residual epilogue -> d_out (512 thr) ----------
__global__ __launch_bounds__(512) void k_cross2(const uint16_t* __restrict__ Prow,
        const uint16_t* __restrict__ PcolT, const uint16_t* __restrict__ VR,
        const uint16_t* __restrict__ VL, const uint16_t* __restrict__ nlr_bf,
        const float* __restrict__ beta, const float* __restrict__ gamma, float* __restrict__ out){
    __shared__ uint16_t VT[192*136];   // 52224 B, reused for VR^T then VL^T
    int bid = blockIdx.x; int b = bid>>7, x = bid&127;
    int tid = threadIdx.x;
    int wv = tid>>6, lane = tid&63, lr = lane&15, lg = lane>>4;   // wv 0..7
    const uint16_t* vrs = VR + (size_t)(b*HWSZ + x*WWD)*CCH;
    const uint16_t* vls = VL + (size_t)(b*HWSZ + x*WWD)*CCH;
    const uint16_t* pr = Prow  + (size_t)(b*128+x)*128*128;
    const uint16_t* pc = PcolT + (size_t)(b*128+x)*128*128;

    for(int idx = tid; idx < 128*24; idx += 512){
        int j = idx / 24, cb = idx % 24;
        uint4 d = *(const uint4*)(vrs + j*CCH + cb*8);
        const uint16_t* dd = (const uint16_t*)&d;
        #pragma unroll
        for(int k=0;k<8;k++) VT[(cb*8+k)*136 + j] = dd[k];
    }
    __syncthreads();
    {
        f32x4 acc[12] = {};
        for(int kk=0; kk<4; kk++){
            int i = wv*16 + lr;
            bf16x8 af = *(const bf16x8*)(pr + i*128 + kk*32 + lg*8);
            #pragma unroll
            for(int nf=0; nf<12; nf++){
                bf16x8 bfr = *(const bf16x8*)(VT + (nf*16+lr)*136 + kk*32 + lg*8);
                acc[nf] = __builtin_amdgcn_mfma_f32_16x16x32_bf16(af, bfr, acc[nf], 0,0,0);
            }
        }
        #pragma unroll
        for(int nf=0; nf<12; nf++){
            int c = nf*16 + lr;
            float bv = beta[c];
            int i0 = wv*16 + lg*4;
            size_t o = ((size_t)(b*CCH + c)*128 + x)*128 + i0;
            const uint16_t* nb = nlr_bf + ((size_t)(b*HWSZ + x*WWD + i0))*CCH + c;
            float4 ov;
            ov.x = bf2f(nb[0*CCH]) + acc[nf][0]*bv;
            ov.y = bf2f(nb[1*CCH]) + acc[nf][1]*bv;
            ov.z = bf2f(nb[2*CCH]) + acc[nf][2]*bv;
            ov.w = bf2f(nb[3*CCH]) + acc[nf][3]*bv;
            *(float4*)(out + o) = ov;
        }
    }
    __syncthreads();
    for(int idx = tid; idx < 128*24; idx += 512){
        int j = idx / 24, cb = idx % 24;
        uint4 d = *(const uint4*)(vls + j*CCH + cb*8);
        const uint16_t* dd = (const uint16_t*)&d;
        #pragma unroll
        for(int k=0;k<8;k++) VT[(cb*8+k)*136 + j] = dd[k];
    }
    __syncthreads();
    {
        f32x4 acc[12] = {};
        for(int kk=0; kk<4; kk++){
            int j = wv*16 + lr;
            bf16x8 af = *(const bf16x8*)(pc + j*128 + kk*32 + lg*8);
            #pragma unroll
            for(int nf=0; nf<12; nf++){
                bf16x8 bfr = *(const bf16x8*)(VT + (nf*16+lr)*136 + kk*32 + lg*8);
                acc[nf] = __builtin_amdgcn_mfma_f32_16x16x32_bf16(af, bfr, acc[nf], 0,0,0);
            }
        }
        float* outr = out + 6291456;
        #pragma unroll
        for(int nf=0; nf<12; nf++){
            int c = nf*16 + lr;
            float gv = gamma[c];
            int j0 = wv*16 + lg*4;
            size_t o = ((size_t)(b*CCH + c)*128 + x)*128 + j0;
            const uint16_t* nb = nlr_bf + ((size_t)(NPOS_SIDE + b*HWSZ + x*WWD + j0))*CCH + c;
            float4 ov;
            ov.x = bf2f(nb[0*CCH]) + acc[nf][0]*gv;
            ov.y = bf2f(nb[1*CCH]) + acc[nf][1]*gv;
            ov.z = bf2f(nb[2*CCH]) + acc[nf][2]*gv;
            ov.w = bf2f(nb[3*CCH]) + acc[nf][3]*gv;
            *(float4*)(outr + o) = ov;
        }
    }
}

// ---------- launch ----------
extern "C" void kernel_launch(void* const* d_in, const int* in_sizes, int n_in,
                              void* d_out, int out_size, void* d_ws, size_t ws_size,
                              hipStream_t stream){
    const float* x_l   = (const float*)d_in[0];
    const float* x_r   = (const float*)d_in[1];
    const float* qkv_w = (const float*)d_in[2];
    const float* qkv_b = (const float*)d_in[3];
    const float* rpb   = (const float*)d_in[4];
    const float* gl    = (const float*)d_in[5];
    const float* bl    = (const float*)d_in[6];
    const float* gr    = (const float*)d_in[7];
    const float* br    = (const float*)d_in[8];
    const float* lp1w  = (const float*)d_in[9];
    const float* lp1b  = (const float*)d_in[10];
    const float* rp1w  = (const float*)d_in[11];
    const float* rp1b  = (const float*)d_in[12];
    const float* lp2w  = (const float*)d_in[13];
    const float* lp2b  = (const float*)d_in[14];
    const float* rp2w  = (const float*)d_in[15];
    const float* rp2b  = (const float*)d_in[16];
    const float* beta  = (const float*)d_in[17];
    const float* gamma = (const float*)d_in[18];
    float* out = (float*)d_out;

    char* ws = (char*)d_ws;
    uint16_t* nlr_bf  = (uint16_t*)(ws + 0);            // 25165824 B
    uint16_t* qkv_bf  = (uint16_t*)(ws + 25165824);     // 75497472 B
    uint16_t* x2      = (uint16_t*)(ws + 25165824);     // alias
    uint16_t* QLb     = (uint16_t*)(ws + 50331648);
    uint16_t* QRb     = (uint16_t*)(ws + 62914560);
    uint16_t* Prow    = (uint16_t*)(ws + 75497472);
    uint16_t* PcolT   = (uint16_t*)(ws + 83886080);
    uint2*    bias_q  = (uint2*)   (ws + 100663296);
    uint16_t* attout  = (uint16_t*)(ws + 102432768);
    uint16_t* VLb     = (uint16_t*)(ws + 102432768);    // alias
    uint16_t* VRb     = (uint16_t*)(ws + 115015680);
    uint16_t* wq      = (uint16_t*)(ws + 127598592);
    uint16_t* w1l     = (uint16_t*)(ws + 127819776);
    uint16_t* w1r     = (uint16_t*)(ws + 127893504);
    uint16_t* w2l     = (uint16_t*)(ws + 127967232);
    uint16_t* w2r     = (uint16_t*)(ws + 128040960);

    k_cvtw<<<dim3(432,5), 256, 0, stream>>>(qkv_w, lp1w, rp1w, lp2w, rp2w, wq, w1l, w1r, w2l, w2r);
    k_bias<<<864, 256, 0, stream>>>(rpb, bias_q);
    k_ln1<<<1024, 256, 0, stream>>>(x_l, x_r, gl, bl, gr, br, nlr_bf);
    k_gemmw<<<dim3(3, 512), 256, 0, stream>>>(nlr_bf, wq, qkv_b, qkv_bf, 192, 576);
    k_attn<<<1536, 256, 0, stream>>>(qkv_bf, bias_q, attout);
    k_ln2<<<16384, 256, 0, stream>>>(attout, gl, bl, gr, br, x2);
    k_gemm4<<<dim3(3, 256, 4), 256, 0, stream>>>(x2, nlr_bf, w1l, w1r, w2l, w2r,
                                                 lp1b, rp1b, lp2b, rp2b, QLb, QRb, VLb, VRb);
    k_cross1<<<256, 512, 0, stream>>>(QLb, QRb, Prow, PcolT);
    k_cross2<<<256, 512, 0, stream>>>(Prow, PcolT, VRb, VLb, nlr_bf, beta, gamma, out);
}

// Round 19
// 349.762 us; speedup vs baseline: 1.3072x; 1.3072x over previous
//
#include <hip/hip_runtime.h>
#include <stdint.h>

// ---------- types / helpers ----------
typedef short bf16x8 __attribute__((ext_vector_type(8)));
typedef float f32x4 __attribute__((ext_vector_type(4)));

__device__ inline float bf2f(uint16_t u){ uint32_t v = ((uint32_t)u)<<16; float f; __builtin_memcpy(&f,&v,4); return f; }
__device__ inline float ubf(uint32_t u){ float f; __builtin_memcpy(&f,&u,4); return f; }
__device__ inline uint16_t f2bf(float f){ uint32_t u; __builtin_memcpy(&u,&f,4); u += 0x7fffu + ((u>>16)&1u); return (uint16_t)(u>>16); }
// round-half-up bf16 (2 ops), for P-pack only
__device__ inline uint16_t f2bfr(float f){ uint32_t u; __builtin_memcpy(&u,&f,4); return (uint16_t)((u + 0x8000u)>>16); }

#define CCH   192
#define HH    128
#define WWD   128
#define HWSZ  16384      // 128*128
#define NPOS_SIDE 32768  // 2*16384
#define NPOS  65536
#define NKT   576
#define SCALE_F 0.17677669529663687f
#define SCALE2_F 0.2550348727f      // SCALE * log2(e)

// ---------- kernel 1: convert weights fp32->bf16 ----------
__global__ __launch_bounds__(256) void k_cvtw(const float* qkvw, const float* l1, const float* r1,
        const float* l2, const float* r2,
        uint16_t* wq, uint16_t* w1l, uint16_t* w1r, uint16_t* w2l, uint16_t* w2r){
    int which = blockIdx.y;
    int i = blockIdx.x*256 + threadIdx.x;
    const float* src; uint16_t* dst; int n;
    switch(which){
      case 0: src=qkvw; dst=wq;  n=576*192; break;
      case 1: src=l1;   dst=w1l; n=192*192; break;
      case 2: src=r1;   dst=w1r; n=192*192; break;
      case 3: src=l2;   dst=w2l; n=192*192; break;
      default:src=r2;   dst=w2r; n=192*192; break;
    }
    if(i<n) dst[i] = f2bf(src[i]);
}

// ---------- kernel 2: rel-pos bias, lane-matched layout, PRE-SCALED by log2(e) ----------
// biasQ[h][q][chunk(18)][half(2)][lg(4)] : uint2 = 4 bf16 for kt = c*32 + half*16 + lg*4 + r
__global__ __launch_bounds__(256) void k_bias(const float* rpb, uint2* biasQ){
    int e = blockIdx.x*256 + threadIdx.x;
    if(e >= 6*256*18*8) return;
    int k = e & 7;              // half*4 + lg
    int c = (e >> 3) % 18;
    int q = ((e >> 3) / 18) % 256;
    int h = e / (8*18*256);
    int half = k >> 2, lg = k & 3;
    int qi = q >> 4, qj = q & 15;
    uint32_t w0 = 0, w1 = 0;
    #pragma unroll
    for(int r=0;r<4;r++){
        int kt = c*32 + half*16 + lg*4 + r;
        int ki = kt/24, kj = kt%24;
        int id = (ki - qi - 7)*39 + (kj - qj - 7);
        id %= 1521; if(id < 0) id += 1521;
        uint32_t bv = f2bf(rpb[id*6 + h] * 1.4426950408889634f);
        if(r < 2) w0 |= bv << (16*r); else w1 |= bv << (16*(r-2));
    }
    biasQ[e] = make_uint2(w0, w1);
}

// ---------- kernel 3: LN over C, single-read LDS-tiled (64 pos x 192 c) ----------
#define LNP 65
__global__ __launch_bounds__(256) void k_ln1(const float* xl, const float* xr,
        const float* gl, const float* bl, const float* gr, const float* br,
        uint16_t* nlr_bf){
    __shared__ float L[192*LNP];       // 49920 B
    __shared__ float redA[4][64];
    __shared__ float redB[4][64];
    __shared__ float mrs[2][64];
    int pos0 = blockIdx.x * 64;        // 1024 blocks
    int s   = pos0 >> 15;
    int loc = pos0 & 32767;
    const float* x = s ? xr : xl;
    const float* g = s ? gr : gl;
    const float* b = s ? br : bl;
    int bb = loc >> 14, hw0 = loc & 16383;
    const float* xp = x + (size_t)bb*CCH*HWSZ + hw0;
    int tid = threadIdx.x;
    {   // load tile (coalesced 256B rows)
        int p = tid & 63, cq = tid >> 6;
        for(int c = cq; c < 192; c += 4)
            L[c*LNP + p] = xp[(size_t)c*HWSZ + p];
    }
    __syncthreads();
    {   // partial sums: 4 threads per position over c-quarters
        int p = tid & 63, part = tid >> 6;
        float sum = 0.f, sq = 0.f;
        for(int c = part*48; c < part*48+48; c++){
            float v = L[c*LNP + p];
            sum += v; sq += v*v;
        }
        redA[part][p] = sum; redB[part][p] = sq;
    }
    __syncthreads();
    if(tid < 64){
        int p = tid;
        float sum = redA[0][p]+redA[1][p]+redA[2][p]+redA[3][p];
        float sq  = redB[0][p]+redB[1][p]+redB[2][p]+redB[3][p];
        float mean = sum*(1.f/192.f);
        float var  = sq*(1.f/192.f) - mean*mean;
        mrs[0][p] = mean;
        mrs[1][p] = rsqrtf(var + 1e-6f);
    }
    __syncthreads();
    {   // output: 4 threads per position, 48 c each as 6 x 16B stores
        int p = tid >> 2, tp = tid & 3;
        float mean = mrs[0][p], rstd = mrs[1][p];
        uint16_t* obp = nlr_bf + (size_t)(pos0 + p)*CCH + tp*48;
        for(int cb = 0; cb < 6; cb++){
            alignas(16) uint16_t tmp[8];
            #pragma unroll
            for(int k=0;k<8;k++){
                int c = tp*48 + cb*8 + k;
                float y = (L[c*LNP + p]-mean)*rstd*g[c] + b[c];
                tmp[k] = f2bf(y);
            }
            *(uint4*)(obp + cb*8) = *(const uint4*)tmp;
        }
    }
}

// ---------- kernel 4a: merged 192x192 conv GEMMs (z selects which of 4) ----------
__global__ __launch_bounds__(256) void k_gemm4(const uint16_t* __restrict__ x2,
        const uint16_t* __restrict__ nlr_bf,
        const uint16_t* __restrict__ w1l, const uint16_t* __restrict__ w1r,
        const uint16_t* __restrict__ w2l, const uint16_t* __restrict__ w2r,
        const float* __restrict__ lp1b, const float* __restrict__ rp1b,
        const float* __restrict__ lp2b, const float* __restrict__ rp2b,
        uint16_t* __restrict__ QLb, uint16_t* __restrict__ QRb,
        uint16_t* __restrict__ VLb, uint16_t* __restrict__ VRb){
    const int K = 192, N = 192;
    int z = blockIdx.z;
    const uint16_t* A; const uint16_t* W; const float* bias; uint16_t* out;
    switch(z){
      case 0: A = x2;                          W = w1l; bias = lp1b; out = QLb; break;
      case 1: A = x2 + (size_t)32768*192;      W = w1r; bias = rp1b; out = QRb; break;
      case 2: A = nlr_bf;                      W = w2l; bias = lp2b; out = VLb; break;
      default:A = nlr_bf + (size_t)32768*192;  W = w2r; bias = rp2b; out = VRb; break;
    }
    int tid = threadIdx.x;
    int w = tid >> 6, lane = tid & 63;
    int lr = lane & 15, lg = lane >> 4;
    int row0 = blockIdx.y*128 + w*16;
    int col0 = blockIdx.x*64;
    const uint16_t* Ap0 = A + (size_t)(row0 + lr)*K + lg*8;
    const uint16_t* Ap1 = Ap0 + (size_t)64*K;
    const uint16_t* Wp = W + (size_t)col0*K + lg*8;
    f32x4 acc[2][4] = {};
    for(int kk=0; kk<6; kk++){
        bf16x8 a0 = *(const bf16x8*)(Ap0 + kk*32);
        bf16x8 a1 = *(const bf16x8*)(Ap1 + kk*32);
        #pragma unroll
        for(int nf=0; nf<4; nf++){
            bf16x8 bfr = *(const bf16x8*)(Wp + (size_t)(nf*16 + lr)*K + kk*32);
            acc[0][nf] = __builtin_amdgcn_mfma_f32_16x16x32_bf16(a0, bfr, acc[0][nf], 0,0,0);
            acc[1][nf] = __builtin_amdgcn_mfma_f32_16x16x32_bf16(a1, bfr, acc[1][nf], 0,0,0);
        }
    }
    #pragma unroll
    for(int nf=0; nf<4; nf++){
        int col = col0 + nf*16 + lr;
        float bv = bias[col];
        #pragma unroll
        for(int m=0; m<2; m++){
            #pragma unroll
            for(int r=0;r<4;r++){
                int row = row0 + m*64 + lg*4 + r;
                out[(size_t)row*N + col] = f2bf(acc[m][nf][r] + bv);
            }
        }
    }
}

// ---------- kernel 4b: GEMM (192-col tiles) for the qkv projection ----------
__global__ __launch_bounds__(256) void k_gemmw(const uint16_t* __restrict__ A,
        const uint16_t* __restrict__ W, const float* __restrict__ bias,
        uint16_t* __restrict__ out, int K, int N){
    int tid = threadIdx.x;
    int w = tid >> 6, lane = tid & 63;
    int lr = lane & 15, lg = lane >> 4;
    int row0 = blockIdx.y*128 + w*16;
    int col0 = blockIdx.x*192;
    const uint16_t* Ap0 = A + (size_t)(row0 + lr)*K + lg*8;
    const uint16_t* Ap1 = Ap0 + (size_t)64*K;
    const uint16_t* Wp = W + (size_t)col0*K + lg*8;
    f32x4 acc[2][12] = {};
    int ksteps = K >> 5;
    for(int kk=0; kk<ksteps; kk++){
        bf16x8 a0 = *(const bf16x8*)(Ap0 + kk*32);
        bf16x8 a1 = *(const bf16x8*)(Ap1 + kk*32);
        #pragma unroll
        for(int nf=0; nf<12; nf++){
            bf16x8 bfr = *(const bf16x8*)(Wp + (size_t)(nf*16 + lr)*K + kk*32);
            acc[0][nf] = __builtin_amdgcn_mfma_f32_16x16x32_bf16(a0, bfr, acc[0][nf], 0,0,0);
            acc[1][nf] = __builtin_amdgcn_mfma_f32_16x16x32_bf16(a1, bfr, acc[1][nf], 0,0,0);
        }
    }
    #pragma unroll
    for(int nf=0; nf<12; nf++){
        int col = col0 + nf*16 + lr;
        float bv = bias[col];
        #pragma unroll
        for(int m=0; m<2; m++){
            #pragma unroll
            for(int r=0;r<4;r++){
                int row = row0 + m*64 + lg*4 + r;
                out[(size_t)row*N + col] = f2bf(acc[m][nf][r] + bv);
            }
        }
    }
}

// ---------- kernel 5: overlapping-window attention (swapped QK^T, lane-local P) ----------
// 256 thr = 4 waves, each wave 64 q-rows. 3 stages of 192 kt. (R13/R14/R17-proven form)
#define KPAD 40
#define STG  192
#define VTP  200
__global__ __launch_bounds__(256) void k_attn(const uint16_t* __restrict__ qkv,
        const uint2* __restrict__ biasQ, uint16_t* __restrict__ attout){
    __shared__ uint16_t Ks[STG*KPAD];      // 15360 B
    __shared__ uint16_t Vt[32*VTP];        // 12800 B  [d][kt-slot-permuted]

    int bid = blockIdx.x;                  // 1536
    int s = bid / 768; int r1 = bid % 768;
    int b = r1 / 384;  int r2 = r1 % 384;
    int head = r2 / 64; int win = r2 % 64;
    int hb = win >> 3, wb = win & 7;
    int tid = threadIdx.x;
    int posbase = s*NPOS_SIDE + b*HWSZ;

    int wv = tid >> 6, lane = tid & 63;
    int lr = lane & 15, lg = lane >> 4;

    bf16x8 qB[4];
    #pragma unroll
    for(int f=0; f<4; f++){
        int t = wv*64 + f*16 + lr;
        int pos = posbase + (hb*16 + (t>>4))*WWD + (wb*16 + (t&15));
        qB[f] = *(const bf16x8*)(qkv + (size_t)pos*NKT + head*32 + lg*8);
    }

    f32x4 acc[4][2] = {};
    float psum[4] = {0.f, 0.f, 0.f, 0.f};

    const uint16_t* kvbase = qkv + (size_t)posbase*NKT;
    const uint2* biasH = biasQ + (size_t)head*256*18*8;

    for(int stg=0; stg<3; stg++){
        __syncthreads();
        for(int idx = tid; idx < STG*4; idx += 256){
            int ktl = idx >> 2, part = idx & 3;
            int ktg = stg*STG + ktl;
            int i = ktg/24, j = ktg%24;
            int h = hb*16 + i - 4, wv2 = wb*16 + j - 4;
            uint4 kd = {0,0,0,0}, vd = {0,0,0,0};
            if((unsigned)h < 128u && (unsigned)wv2 < 128u){
                const uint16_t* p = kvbase + (size_t)(h*WWD + wv2)*NKT + 192 + head*32 + part*8;
                kd = *(const uint4*)p;
                vd = *(const uint4*)(p + 192);
            }
            *(uint4*)(Ks + ktl*KPAD + part*8) = kd;
            int t32 = ktl & 31;
            int ktp = (ktl & ~31) + (((t32&12)<<1) + ((t32>>4)<<2) + (t32&3));
            const uint16_t* vs = (const uint16_t*)&vd;
            #pragma unroll
            for(int k2=0;k2<8;k2++) Vt[(part*8+k2)*VTP + ktp] = vs[k2];
        }
        __syncthreads();

        for(int kc=0; kc<6; kc++){
            int kt0 = kc*32;
            int cg  = stg*6 + kc;
            bf16x8 k0 = *(const bf16x8*)(Ks + (kt0 + lr)*KPAD + lg*8);
            bf16x8 k1 = *(const bf16x8*)(Ks + (kt0 + 16 + lr)*KPAD + lg*8);
            bf16x8 vb0 = *(const bf16x8*)(Vt + lr*VTP        + kt0 + lg*8);
            bf16x8 vb1 = *(const bf16x8*)(Vt + (16+lr)*VTP   + kt0 + lg*8);

            #pragma unroll
            for(int f=0; f<4; f++){
                f32x4 z = {0.f,0.f,0.f,0.f};
                f32x4 s0 = __builtin_amdgcn_mfma_f32_16x16x32_bf16(k0, qB[f], z, 0,0,0);
                f32x4 s1 = __builtin_amdgcn_mfma_f32_16x16x32_bf16(k1, qB[f], z, 0,0,0);
                int q = wv*64 + f*16 + lr;
                const uint2* bq = biasH + ((size_t)q*18 + cg)*8;
                uint2 bh0 = bq[lg];
                uint2 bh1 = bq[4 + lg];
                float e0 = exp2f(__builtin_fmaf(s0[0], SCALE2_F, ubf(bh0.x << 16)));
                float e1 = exp2f(__builtin_fmaf(s0[1], SCALE2_F, ubf(bh0.x & 0xffff0000u)));
                float e2 = exp2f(__builtin_fmaf(s0[2], SCALE2_F, ubf(bh0.y << 16)));
                float e3 = exp2f(__builtin_fmaf(s0[3], SCALE2_F, ubf(bh0.y & 0xffff0000u)));
                float e4 = exp2f(__builtin_fmaf(s1[0], SCALE2_F, ubf(bh1.x << 16)));
                float e5 = exp2f(__builtin_fmaf(s1[1], SCALE2_F, ubf(bh1.x & 0xffff0000u)));
                float e6 = exp2f(__builtin_fmaf(s1[2], SCALE2_F, ubf(bh1.y << 16)));
                float e7 = exp2f(__builtin_fmaf(s1[3], SCALE2_F, ubf(bh1.y & 0xffff0000u)));
                psum[f] += ((e0+e1)+(e2+e3)) + ((e4+e5)+(e6+e7));
                bf16x8 pv;
                pv[0] = (short)f2bfr(e0); pv[1] = (short)f2bfr(e1);
                pv[2] = (short)f2bfr(e2); pv[3] = (short)f2bfr(e3);
                pv[4] = (short)f2bfr(e4); pv[5] = (short)f2bfr(e5);
                pv[6] = (short)f2bfr(e6); pv[7] = (short)f2bfr(e7);
                acc[f][0] = __builtin_amdgcn_mfma_f32_16x16x32_bf16(pv, vb0, acc[f][0], 0,0,0);
                acc[f][1] = __builtin_amdgcn_mfma_f32_16x16x32_bf16(pv, vb1, acc[f][1], 0,0,0);
            }
        }
    }

    #pragma unroll
    for(int f=0; f<4; f++){
        float dsum = psum[f];
        dsum += __shfl_xor(dsum, 16);
        dsum += __shfl_xor(dsum, 32);
        float invl = 1.f / dsum;
        #pragma unroll
        for(int r=0;r<4;r++){
            float inv = __shfl(invl, 4*lg + r);
            int q = wv*64 + f*16 + 4*lg + r;
            int pos = posbase + (hb*16 + (q>>4))*WWD + (wb*16 + (q&15));
            #pragma unroll
            for(int n=0;n<2;n++){
                attout[(size_t)pos*CCH + head*32 + n*16 + lr] = f2bf(acc[f][n][r]*inv);
            }
        }
    }
}

// ---------- kernel 6: LN over C of attention output (bf16 rows) -> bf16 rows ----------
__global__ __launch_bounds__(256) void k_ln2(const uint16_t* __restrict__ attout,
        const float* gl, const float* bl, const float* gr, const float* br,
        uint16_t* __restrict__ x2){
    int wv = threadIdx.x >> 6, lane = threadIdx.x & 63;
    int pos = blockIdx.x*4 + wv;
    int s = pos >> 15;
    const float* g = s ? gr : gl;
    const float* b = s ? br : bl;
    const uint16_t* ip = attout + (size_t)pos*CCH;
    float v[3]; float sum=0.f, sq=0.f;
    #pragma unroll
    for(int k=0;k<3;k++){ v[k] = bf2f(ip[lane + 64*k]); sum += v[k]; sq += v[k]*v[k]; }
    #pragma unroll
    for(int m=1;m<64;m<<=1){ sum += __shfl_xor(sum,m); sq += __shfl_xor(sq,m); }
    float mean = sum*(1.f/192.f);
    float var  = sq*(1.f/192.f) - mean*mean;
    float rstd = rsqrtf(var + 1e-6f);
    uint16_t* op = x2 + (size_t)pos*CCH;
    #pragma unroll
    for(int k=0;k<3;k++){
        int c = lane + 64*k;
        op[c] = f2bf((v[k]-mean)*rstd*g[c] + b[c]);
    }
}

// ---------- kernel 7: cross-att scores + both softmaxes; block per (b, x=w), 512 thr ----------
__global__ __launch_bounds__(512) void k_cross1(const uint16_t* __restrict__ QL,
        const uint16_t* __restrict__ QR, uint16_t* __restrict__ Prow, uint16_t* __restrict__ PcolT){
    __shared__ float S[128*128];  // 64 KB
    __shared__ float cred[4][128];
    __shared__ float colm[128];
    __shared__ float colinv[128];
    int bid = blockIdx.x; int b = bid >> 7, x = bid & 127;
    int tid = threadIdx.x;
    int wv = tid>>6, lane = tid&63, lr = lane&15, lg = lane>>4;   // wv 0..7
    const uint16_t* Abase = QL + (size_t)b*HWSZ*CCH;
    const uint16_t* Bbase = QR + (size_t)b*HWSZ*CCH;
    f32x4 acc[8] = {};
    for(int kk=0; kk<6; kk++){
        int i = wv*16 + lr;
        bf16x8 af = *(const bf16x8*)(Abase + (size_t)(i*WWD + x)*CCH + kk*32 + lg*8);
        #pragma unroll
        for(int nf=0; nf<8; nf++){
            int j = nf*16 + lr;
            bf16x8 bfr = *(const bf16x8*)(Bbase + (size_t)(j*WWD + x)*CCH + kk*32 + lg*8);
            acc[nf] = __builtin_amdgcn_mfma_f32_16x16x32_bf16(af, bfr, acc[nf], 0,0,0);
        }
    }
    #pragma unroll
    for(int nf=0;nf<8;nf++)
    #pragma unroll
    for(int r=0;r<4;r++){
        int i = wv*16 + lg*4 + r; int j = nf*16 + lr;
        S[i*128 + j] = acc[nf][r]*SCALE_F;
    }
    __syncthreads();
    uint16_t* prb = Prow + (size_t)(b*128 + x)*128*128;
    for(int i = wv*16; i < wv*16+16; i++){
        float v0 = S[i*128 + lane], v1 = S[i*128 + 64 + lane];
        float m = fmaxf(v0,v1);
        #pragma unroll
        for(int k=1;k<64;k<<=1) m = fmaxf(m, __shfl_xor(m,k));
        float e0 = __expf(v0-m), e1 = __expf(v1-m);
        float ss = e0+e1;
        #pragma unroll
        for(int k=1;k<64;k<<=1) ss += __shfl_xor(ss,k);
        float inv = 1.f/ss;
        prb[i*128 + lane]      = f2bf(e0*inv);
        prb[i*128 + 64 + lane] = f2bf(e1*inv);
    }
    int j = tid & 127, q4 = tid >> 7;
    int i0 = q4*32;
    float m = -1e30f;
    for(int i=i0; i<i0+32; i++) m = fmaxf(m, S[i*128 + j]);
    cred[q4][j] = m;
    __syncthreads();
    if(tid < 128) colm[tid] = fmaxf(fmaxf(cred[0][tid], cred[1][tid]), fmaxf(cred[2][tid], cred[3][tid]));
    __syncthreads();
    float mj = colm[j];
    float ssum = 0.f;
    for(int i=i0; i<i0+32; i++) ssum += __expf(S[i*128 + j] - mj);
    cred[q4][j] = ssum;
    __syncthreads();
    if(tid < 128) colinv[tid] = 1.f/(cred[0][tid] + cred[1][tid] + cred[2][tid] + cred[3][tid]);
    __syncthreads();
    float cinv = colinv[j];
    uint16_t* pcb = PcolT + (size_t)(b*128 + x)*128*128;
    for(int i=i0; i<i0+32; i++) pcb[j*128 + i] = f2bf(__expf(S[i*128 + j] - mj)*cinv);
}

// ---------- kernel 8: PV GEMMs + residual epilogue -> d_out (512 thr) ----------
__global__ __launch_bounds__(512) void k_cross2(const uint16_t* __restrict__ Prow,
        const uint16_t* __restrict__ PcolT, const uint16_t* __restrict__ VR,
        const uint16_t* __restrict__ VL, const uint16_t* __restrict__ nlr_bf,
        const float* __restrict__ beta, const float* __restrict__ gamma, float* __restrict__ out){
    __shared__ uint16_t VT[192*136];   // 52224 B, reused for VR^T then VL^T
    int bid = blockIdx.x; int b = bid>>7, x = bid&127;
    int tid = threadIdx.x;
    int wv = tid>>6, lane = tid&63, lr = lane&15, lg = lane>>4;   // wv 0..7
    const uint16_t* vrs = VR + (size_t)(b*HWSZ + x*WWD)*CCH;
    const uint16_t* vls = VL + (size_t)(b*HWSZ + x*WWD)*CCH;
    const uint16_t* pr = Prow  + (size_t)(b*128+x)*128*128;
    const uint16_t* pc = PcolT + (size_t)(b*128+x)*128*128;

    for(int idx = tid; idx < 128*24; idx += 512){
        int j = idx / 24, cb = idx % 24;
        uint4 d = *(const uint4*)(vrs + j*CCH + cb*8);
        const uint16_t* dd = (const uint16_t*)&d;
        #pragma unroll
        for(int k=0;k<8;k++) VT[(cb*8+k)*136 + j] = dd[k];
    }
    __syncthreads();
    {
        f32x4 acc[12] = {};
        for(int kk=0; kk<4; kk++){
            int i = wv*16 + lr;
            bf16x8 af = *(const bf16x8*)(pr + i*128 + kk*32 + lg*8);
            #pragma unroll
            for(int nf=0; nf<12; nf++){
                bf16x8 bfr = *(const bf16x8*)(VT + (nf*16+lr)*136 + kk*32 + lg*8);
                acc[nf] = __builtin_amdgcn_mfma_f32_16x16x32_bf16(af, bfr, acc[nf], 0,0,0);
            }
        }
        #pragma unroll
        for(int nf=0; nf<12; nf++){
            int c = nf*16 + lr;
            float bv = beta[c];
            int i0 = wv*16 + lg*4;
            size_t o = ((size_t)(b*CCH + c)*128 + x)*128 + i0;
            const uint16_t* nb = nlr_bf + ((size_t)(b*HWSZ + x*WWD + i0))*CCH + c;
            float4 ov;
            ov.x = bf2f(nb[0*CCH]) + acc[nf][0]*bv;
            ov.y = bf2f(nb[1*CCH]) + acc[nf][1]*bv;
            ov.z = bf2f(nb[2*CCH]) + acc[nf][2]*bv;
            ov.w = bf2f(nb[3*CCH]) + acc[nf][3]*bv;
            *(float4*)(out + o) = ov;
        }
    }
    __syncthreads();
    for(int idx = tid; idx < 128*24; idx += 512){
        int j = idx / 24, cb = idx % 24;
        uint4 d = *(const uint4*)(vls + j*CCH + cb*8);
        const uint16_t* dd = (const uint16_t*)&d;
        #pragma unroll
        for(int k=0;k<8;k++) VT[(cb*8+k)*136 + j] = dd[k];
    }
    __syncthreads();
    {
        f32x4 acc[12] = {};
        for(int kk=0; kk<4; kk++){
            int j = wv*16 + lr;
            bf16x8 af = *(const bf16x8*)(pc + j*128 + kk*32 + lg*8);
            #pragma unroll
            for(int nf=0; nf<12; nf++){
                bf16x8 bfr = *(const bf16x8*)(VT + (nf*16+lr)*136 + kk*32 + lg*8);
                acc[nf] = __builtin_amdgcn_mfma_f32_16x16x32_bf16(af, bfr, acc[nf], 0,0,0);
            }
        }
        float* outr = out + 6291456;
        #pragma unroll
        for(int nf=0; nf<12; nf++){
            int c = nf*16 + lr;
            float gv = gamma[c];
            int j0 = wv*16 + lg*4;
            size_t o = ((size_t)(b*CCH + c)*128 + x)*128 + j0;
            const uint16_t* nb = nlr_bf + ((size_t)(NPOS_SIDE + b*HWSZ + x*WWD + j0))*CCH + c;
            float4 ov;
            ov.x = bf2f(nb[0*CCH]) + acc[nf][0]*gv;
            ov.y = bf2f(nb[1*CCH]) + acc[nf][1]*gv;
            ov.z = bf2f(nb[2*CCH]) + acc[nf][2]*gv;
            ov.w = bf2f(nb[3*CCH]) + acc[nf][3]*gv;
            *(float4*)(outr + o) = ov;
        }
    }
}

// ---------- launch ----------
extern "C" void kernel_launch(void* const* d_in, const int* in_sizes, int n_in,
                              void* d_out, int out_size, void* d_ws, size_t ws_size,
                              hipStream_t stream){
    const float* x_l   = (const float*)d_in[0];
    const float* x_r   = (const float*)d_in[1];
    const float* qkv_w = (const float*)d_in[2];
    const float* qkv_b = (const float*)d_in[3];
    const float* rpb   = (const float*)d_in[4];
    const float* gl    = (const float*)d_in[5];
    const float* bl    = (const float*)d_in[6];
    const float* gr    = (const float*)d_in[7];
    const float* br    = (const float*)d_in[8];
    const float* lp1w  = (const float*)d_in[9];
    const float* lp1b  = (const float*)d_in[10];
    const float* rp1w  = (const float*)d_in[11];
    const float* rp1b  = (const float*)d_in[12];
    const float* lp2w  = (const float*)d_in[13];
    const float* lp2b  = (const float*)d_in[14];
    const float* rp2w  = (const float*)d_in[15];
    const float* rp2b  = (const float*)d_in[16];
    const float* beta  = (const float*)d_in[17];
    const float* gamma = (const float*)d_in[18];
    float* out = (float*)d_out;

    char* ws = (char*)d_ws;
    uint16_t* nlr_bf  = (uint16_t*)(ws + 0);            // 25165824 B
    uint16_t* qkv_bf  = (uint16_t*)(ws + 25165824);     // 75497472 B
    uint16_t* x2      = (uint16_t*)(ws + 25165824);     // alias
    uint16_t* QLb     = (uint16_t*)(ws + 50331648);
    uint16_t* QRb     = (uint16_t*)(ws + 62914560);
    uint16_t* Prow    = (uint16_t*)(ws + 75497472);
    uint16_t* PcolT   = (uint16_t*)(ws + 83886080);
    uint2*    bias_q  = (uint2*)   (ws + 100663296);
    uint16_t* attout  = (uint16_t*)(ws + 102432768);
    uint16_t* VLb     = (uint16_t*)(ws + 102432768);    // alias
    uint16_t* VRb     = (uint16_t*)(ws + 115015680);
    uint16_t* wq      = (uint16_t*)(ws + 127598592);
    uint16_t* w1l     = (uint16_t*)(ws + 127819776);
    uint16_t* w1r     = (uint16_t*)(ws + 127893504);
    uint16_t* w2l     = (uint16_t*)(ws + 127967232);
    uint16_t* w2r     = (uint16_t*)(ws + 128040960);

    k_cvtw<<<dim3(432,5), 256, 0, stream>>>(qkv_w, lp1w, rp1w, lp2w, rp2w, wq, w1l, w1r, w2l, w2r);
    k_bias<<<864, 256, 0, stream>>>(rpb, bias_q);
    k_ln1<<<1024, 256, 0, stream>>>(x_l, x_r, gl, bl, gr, br, nlr_bf);
    k_gemmw<<<dim3(3, 512), 256, 0, stream>>>(nlr_bf, wq, qkv_b, qkv_bf, 192, 576);
    k_attn<<<1536, 256, 0, stream>>>(qkv_bf, bias_q, attout);
    k_ln2<<<16384, 256, 0, stream>>>(attout, gl, bl, gr, br, x2);
    k_gemm4<<<dim3(3, 256, 4), 256, 0, stream>>>(x2, nlr_bf, w1l, w1r, w2l, w2r,
                                                 lp1b, rp1b, lp2b, rp2b, QLb, QRb, VLb, VRb);
    k_cross1<<<256, 512, 0, stream>>>(QLb, QRb, Prow, PcolT);
    k_cross2<<<256, 512, 0, stream>>>(Prow, PcolT, VRb, VLb, nlr_bf, beta, gamma, out);
}

// Round 20
// 349.542 us; speedup vs baseline: 1.3080x; 1.0006x over previous
//
#include <hip/hip_runtime.h>
#include <stdint.h>

// ---------- types / helpers ----------
typedef short bf16x8 __attribute__((ext_vector_type(8)));
typedef float f32x4 __attribute__((ext_vector_type(4)));

__device__ inline float bf2f(uint16_t u){ uint32_t v = ((uint32_t)u)<<16; float f; __builtin_memcpy(&f,&v,4); return f; }
__device__ inline float ubf(uint32_t u){ float f; __builtin_memcpy(&f,&u,4); return f; }
__device__ inline uint16_t f2bf(float f){ uint32_t u; __builtin_memcpy(&u,&f,4); u += 0x7fffu + ((u>>16)&1u); return (uint16_t)(u>>16); }
// round-half-up bf16 (2 ops), for P-pack only
__device__ inline uint16_t f2bfr(float f){ uint32_t u; __builtin_memcpy(&u,&f,4); return (uint16_t)((u + 0x8000u)>>16); }

#define CCH   192
#define HH    128
#define WWD   128
#define HWSZ  16384      // 128*128
#define NPOS_SIDE 32768  // 2*16384
#define NPOS  65536
#define NKT   576
#define SCALE_F 0.17677669529663687f
#define SCALE2_F 0.2550348727f      // SCALE * log2(e)

// ---------- kernel 1: convert weights fp32->bf16 ----------
__global__ __launch_bounds__(256) void k_cvtw(const float* qkvw, const float* l1, const float* r1,
        const float* l2, const float* r2,
        uint16_t* wq, uint16_t* w1l, uint16_t* w1r, uint16_t* w2l, uint16_t* w2r){
    int which = blockIdx.y;
    int i = blockIdx.x*256 + threadIdx.x;
    const float* src; uint16_t* dst; int n;
    switch(which){
      case 0: src=qkvw; dst=wq;  n=576*192; break;
      case 1: src=l1;   dst=w1l; n=192*192; break;
      case 2: src=r1;   dst=w1r; n=192*192; break;
      case 3: src=l2;   dst=w2l; n=192*192; break;
      default:src=r2;   dst=w2r; n=192*192; break;
    }
    if(i<n) dst[i] = f2bf(src[i]);
}

// ---------- kernel 2: rel-pos bias, lane-matched layout, PRE-SCALED by log2(e) ----------
// biasQ[h][q][chunk(18)][half(2)][lg(4)] : uint2 = 4 bf16 for kt = c*32 + half*16 + lg*4 + r
__global__ __launch_bounds__(256) void k_bias(const float* rpb, uint2* biasQ){
    int e = blockIdx.x*256 + threadIdx.x;
    if(e >= 6*256*18*8) return;
    int k = e & 7;              // half*4 + lg
    int c = (e >> 3) % 18;
    int q = ((e >> 3) / 18) % 256;
    int h = e / (8*18*256);
    int half = k >> 2, lg = k & 3;
    int qi = q >> 4, qj = q & 15;
    uint32_t w0 = 0, w1 = 0;
    #pragma unroll
    for(int r=0;r<4;r++){
        int kt = c*32 + half*16 + lg*4 + r;
        int ki = kt/24, kj = kt%24;
        int id = (ki - qi - 7)*39 + (kj - qj - 7);
        id %= 1521; if(id < 0) id += 1521;
        uint32_t bv = f2bf(rpb[id*6 + h] * 1.4426950408889634f);
        if(r < 2) w0 |= bv << (16*r); else w1 |= bv << (16*(r-2));
    }
    biasQ[e] = make_uint2(w0, w1);
}

// ---------- kernel 3: LN over C, single-read LDS-tiled (64 pos x 192 c) ----------
#define LNP 65
__global__ __launch_bounds__(256) void k_ln1(const float* xl, const float* xr,
        const float* gl, const float* bl, const float* gr, const float* br,
        uint16_t* nlr_bf){
    __shared__ float L[192*LNP];       // 49920 B
    __shared__ float redA[4][64];
    __shared__ float redB[4][64];
    __shared__ float mrs[2][64];
    int pos0 = blockIdx.x * 64;        // 1024 blocks
    int s   = pos0 >> 15;
    int loc = pos0 & 32767;
    const float* x = s ? xr : xl;
    const float* g = s ? gr : gl;
    const float* b = s ? br : bl;
    int bb = loc >> 14, hw0 = loc & 16383;
    const float* xp = x + (size_t)bb*CCH*HWSZ + hw0;
    int tid = threadIdx.x;
    {   // load tile (coalesced 256B rows)
        int p = tid & 63, cq = tid >> 6;
        for(int c = cq; c < 192; c += 4)
            L[c*LNP + p] = xp[(size_t)c*HWSZ + p];
    }
    __syncthreads();
    {   // partial sums: 4 threads per position over c-quarters
        int p = tid & 63, part = tid >> 6;
        float sum = 0.f, sq = 0.f;
        for(int c = part*48; c < part*48+48; c++){
            float v = L[c*LNP + p];
            sum += v; sq += v*v;
        }
        redA[part][p] = sum; redB[part][p] = sq;
    }
    __syncthreads();
    if(tid < 64){
        int p = tid;
        float sum = redA[0][p]+redA[1][p]+redA[2][p]+redA[3][p];
        float sq  = redB[0][p]+redB[1][p]+redB[2][p]+redB[3][p];
        float mean = sum*(1.f/192.f);
        float var  = sq*(1.f/192.f) - mean*mean;
        mrs[0][p] = mean;
        mrs[1][p] = rsqrtf(var + 1e-6f);
    }
    __syncthreads();
    {   // output: 4 threads per position, 48 c each as 6 x 16B stores
        int p = tid >> 2, tp = tid & 3;
        float mean = mrs[0][p], rstd = mrs[1][p];
        uint16_t* obp = nlr_bf + (size_t)(pos0 + p)*CCH + tp*48;
        for(int cb = 0; cb < 6; cb++){
            alignas(16) uint16_t tmp[8];
            #pragma unroll
            for(int k=0;k<8;k++){
                int c = tp*48 + cb*8 + k;
                float y = (L[c*LNP + p]-mean)*rstd*g[c] + b[c];
                tmp[k] = f2bf(y);
            }
            *(uint4*)(obp + cb*8) = *(const uint4*)tmp;
        }
    }
}

// ---------- kernel 4a: merged 192x192 conv GEMMs (z selects which of 4) ----------
__global__ __launch_bounds__(256) void k_gemm4(const uint16_t* __restrict__ x2,
        const uint16_t* __restrict__ nlr_bf,
        const uint16_t* __restrict__ w1l, const uint16_t* __restrict__ w1r,
        const uint16_t* __restrict__ w2l, const uint16_t* __restrict__ w2r,
        const float* __restrict__ lp1b, const float* __restrict__ rp1b,
        const float* __restrict__ lp2b, const float* __restrict__ rp2b,
        uint16_t* __restrict__ QLb, uint16_t* __restrict__ QRb,
        uint16_t* __restrict__ VLb, uint16_t* __restrict__ VRb){
    const int K = 192, N = 192;
    int z = blockIdx.z;
    const uint16_t* A; const uint16_t* W; const float* bias; uint16_t* out;
    switch(z){
      case 0: A = x2;                          W = w1l; bias = lp1b; out = QLb; break;
      case 1: A = x2 + (size_t)32768*192;      W = w1r; bias = rp1b; out = QRb; break;
      case 2: A = nlr_bf;                      W = w2l; bias = lp2b; out = VLb; break;
      default:A = nlr_bf + (size_t)32768*192;  W = w2r; bias = rp2b; out = VRb; break;
    }
    int tid = threadIdx.x;
    int w = tid >> 6, lane = tid & 63;
    int lr = lane & 15, lg = lane >> 4;
    int row0 = blockIdx.y*128 + w*16;
    int col0 = blockIdx.x*64;
    const uint16_t* Ap0 = A + (size_t)(row0 + lr)*K + lg*8;
    const uint16_t* Ap1 = Ap0 + (size_t)64*K;
    const uint16_t* Wp = W + (size_t)col0*K + lg*8;
    f32x4 acc[2][4] = {};
    for(int kk=0; kk<6; kk++){
        bf16x8 a0 = *(const bf16x8*)(Ap0 + kk*32);
        bf16x8 a1 = *(const bf16x8*)(Ap1 + kk*32);
        #pragma unroll
        for(int nf=0; nf<4; nf++){
            bf16x8 bfr = *(const bf16x8*)(Wp + (size_t)(nf*16 + lr)*K + kk*32);
            acc[0][nf] = __builtin_amdgcn_mfma_f32_16x16x32_bf16(a0, bfr, acc[0][nf], 0,0,0);
            acc[1][nf] = __builtin_amdgcn_mfma_f32_16x16x32_bf16(a1, bfr, acc[1][nf], 0,0,0);
        }
    }
    #pragma unroll
    for(int nf=0; nf<4; nf++){
        int col = col0 + nf*16 + lr;
        float bv = bias[col];
        #pragma unroll
        for(int m=0; m<2; m++){
            #pragma unroll
            for(int r=0;r<4;r++){
                int row = row0 + m*64 + lg*4 + r;
                out[(size_t)row*N + col] = f2bf(acc[m][nf][r] + bv);
            }
        }
    }
}

// ---------- kernel 4b: GEMM (192-col tiles) for the qkv projection ----------
__global__ __launch_bounds__(256) void k_gemmw(const uint16_t* __restrict__ A,
        const uint16_t* __restrict__ W, const float* __restrict__ bias,
        uint16_t* __restrict__ out, int K, int N){
    int tid = threadIdx.x;
    int w = tid >> 6, lane = tid & 63;
    int lr = lane & 15, lg = lane >> 4;
    int row0 = blockIdx.y*128 + w*16;
    int col0 = blockIdx.x*192;
    const uint16_t* Ap0 = A + (size_t)(row0 + lr)*K + lg*8;
    const uint16_t* Ap1 = Ap0 + (size_t)64*K;
    const uint16_t* Wp = W + (size_t)col0*K + lg*8;
    f32x4 acc[2][12] = {};
    int ksteps = K >> 5;
    for(int kk=0; kk<ksteps; kk++){
        bf16x8 a0 = *(const bf16x8*)(Ap0 + kk*32);
        bf16x8 a1 = *(const bf16x8*)(Ap1 + kk*32);
        #pragma unroll
        for(int nf=0; nf<12; nf++){
            bf16x8 bfr = *(const bf16x8*)(Wp + (size_t)(nf*16 + lr)*K + kk*32);
            acc[0][nf] = __builtin_amdgcn_mfma_f32_16x16x32_bf16(a0, bfr, acc[0][nf], 0,0,0);
            acc[1][nf] = __builtin_amdgcn_mfma_f32_16x16x32_bf16(a1, bfr, acc[1][nf], 0,0,0);
        }
    }
    #pragma unroll
    for(int nf=0; nf<12; nf++){
        int col = col0 + nf*16 + lr;
        float bv = bias[col];
        #pragma unroll
        for(int m=0; m<2; m++){
            #pragma unroll
            for(int r=0;r<4;r++){
                int row = row0 + m*64 + lg*4 + r;
                out[(size_t)row*N + col] = f2bf(acc[m][nf][r] + bv);
            }
        }
    }
}

// ---------- kernel 5: overlapping-window attention (swapped QK^T, lane-local P) ----------
// 256 thr = 4 waves, each wave 64 q-rows. 3 stages of 192 kt. (R13/R14/R17-proven form)
#define KPAD 40
#define STG  192
#define VTP  200
__global__ __launch_bounds__(256) void k_attn(const uint16_t* __restrict__ qkv,
        const uint2* __restrict__ biasQ, uint16_t* __restrict__ attout){
    __shared__ uint16_t Ks[STG*KPAD];      // 15360 B
    __shared__ uint16_t Vt[32*VTP];        // 12800 B  [d][kt-slot-permuted]

    int bid = blockIdx.x;                  // 1536
    int s = bid / 768; int r1 = bid % 768;
    int b = r1 / 384;  int r2 = r1 % 384;
    int head = r2 / 64; int win = r2 % 64;
    int hb = win >> 3, wb = win & 7;
    int tid = threadIdx.x;
    int posbase = s*NPOS_SIDE + b*HWSZ;

    int wv = tid >> 6, lane = tid & 63;
    int lr = lane & 15, lg = lane >> 4;

    bf16x8 qB[4];
    #pragma unroll
    for(int f=0; f<4; f++){
        int t = wv*64 + f*16 + lr;
        int pos = posbase + (hb*16 + (t>>4))*WWD + (wb*16 + (t&15));
        qB[f] = *(const bf16x8*)(qkv + (size_t)pos*NKT + head*32 + lg*8);
    }

    f32x4 acc[4][2] = {};
    float psum[4] = {0.f, 0.f, 0.f, 0.f};

    const uint16_t* kvbase = qkv + (size_t)posbase*NKT;
    const uint2* biasH = biasQ + (size_t)head*256*18*8;

    for(int stg=0; stg<3; stg++){
        __syncthreads();
        for(int idx = tid; idx < STG*4; idx += 256){
            int ktl = idx >> 2, part = idx & 3;
            int ktg = stg*STG + ktl;
            int i = ktg/24, j = ktg%24;
            int h = hb*16 + i - 4, wv2 = wb*16 + j - 4;
            uint4 kd = {0,0,0,0}, vd = {0,0,0,0};
            if((unsigned)h < 128u && (unsigned)wv2 < 128u){
                const uint16_t* p = kvbase + (size_t)(h*WWD + wv2)*NKT + 192 + head*32 + part*8;
                kd = *(const uint4*)p;
                vd = *(const uint4*)(p + 192);
            }
            *(uint4*)(Ks + ktl*KPAD + part*8) = kd;
            int t32 = ktl & 31;
            int ktp = (ktl & ~31) + (((t32&12)<<1) + ((t32>>4)<<2) + (t32&3));
            const uint16_t* vs = (const uint16_t*)&vd;
            #pragma unroll
            for(int k2=0;k2<8;k2++) Vt[(part*8+k2)*VTP + ktp] = vs[k2];
        }
        __syncthreads();

        for(int kc=0; kc<6; kc++){
            int kt0 = kc*32;
            int cg  = stg*6 + kc;
            bf16x8 k0 = *(const bf16x8*)(Ks + (kt0 + lr)*KPAD + lg*8);
            bf16x8 k1 = *(const bf16x8*)(Ks + (kt0 + 16 + lr)*KPAD + lg*8);
            bf16x8 vb0 = *(const bf16x8*)(Vt + lr*VTP        + kt0 + lg*8);
            bf16x8 vb1 = *(const bf16x8*)(Vt + (16+lr)*VTP   + kt0 + lg*8);

            #pragma unroll
            for(int f=0; f<4; f++){
                f32x4 z = {0.f,0.f,0.f,0.f};
                f32x4 s0 = __builtin_amdgcn_mfma_f32_16x16x32_bf16(k0, qB[f], z, 0,0,0);
                f32x4 s1 = __builtin_amdgcn_mfma_f32_16x16x32_bf16(k1, qB[f], z, 0,0,0);
                int q = wv*64 + f*16 + lr;
                const uint2* bq = biasH + ((size_t)q*18 + cg)*8;
                uint2 bh0 = bq[lg];
                uint2 bh1 = bq[4 + lg];
                float e0 = exp2f(__builtin_fmaf(s0[0], SCALE2_F, ubf(bh0.x << 16)));
                float e1 = exp2f(__builtin_fmaf(s0[1], SCALE2_F, ubf(bh0.x & 0xffff0000u)));
                float e2 = exp2f(__builtin_fmaf(s0[2], SCALE2_F, ubf(bh0.y << 16)));
                float e3 = exp2f(__builtin_fmaf(s0[3], SCALE2_F, ubf(bh0.y & 0xffff0000u)));
                float e4 = exp2f(__builtin_fmaf(s1[0], SCALE2_F, ubf(bh1.x << 16)));
                float e5 = exp2f(__builtin_fmaf(s1[1], SCALE2_F, ubf(bh1.x & 0xffff0000u)));
                float e6 = exp2f(__builtin_fmaf(s1[2], SCALE2_F, ubf(bh1.y << 16)));
                float e7 = exp2f(__builtin_fmaf(s1[3], SCALE2_F, ubf(bh1.y & 0xffff0000u)));
                psum[f] += ((e0+e1)+(e2+e3)) + ((e4+e5)+(e6+e7));
                bf16x8 pv;
                pv[0] = (short)f2bfr(e0); pv[1] = (short)f2bfr(e1);
                pv[2] = (short)f2bfr(e2); pv[3] = (short)f2bfr(e3);
                pv[4] = (short)f2bfr(e4); pv[5] = (short)f2bfr(e5);
                pv[6] = (short)f2bfr(e6); pv[7] = (short)f2bfr(e7);
                acc[f][0] = __builtin_amdgcn_mfma_f32_16x16x32_bf16(pv, vb0, acc[f][0], 0,0,0);
                acc[f][1] = __builtin_amdgcn_mfma_f32_16x16x32_bf16(pv, vb1, acc[f][1], 0,0,0);
            }
        }
    }

    #pragma unroll
    for(int f=0; f<4; f++){
        float dsum = psum[f];
        dsum += __shfl_xor(dsum, 16);
        dsum += __shfl_xor(dsum, 32);
        float invl = 1.f / dsum;
        #pragma unroll
        for(int r=0;r<4;r++){
            float inv = __shfl(invl, 4*lg + r);
            int q = wv*64 + f*16 + 4*lg + r;
            int pos = posbase + (hb*16 + (q>>4))*WWD + (wb*16 + (q&15));
            #pragma unroll
            for(int n=0;n<2;n++){
                attout[(size_t)pos*CCH + head*32 + n*16 + lr] = f2bf(acc[f][n][r]*inv);
            }
        }
    }
}

// ---------- kernel 6: LN over C of attention output (bf16 rows) -> bf16 rows ----------
__global__ __launch_bounds__(256) void k_ln2(const uint16_t* __restrict__ attout,
        const float* gl, const float* bl, const float* gr, const float* br,
        uint16_t* __restrict__ x2){
    int wv = threadIdx.x >> 6, lane = threadIdx.x & 63;
    int pos = blockIdx.x*4 + wv;
    int s = pos >> 15;
    const float* g = s ? gr : gl;
    const float* b = s ? br : bl;
    const uint16_t* ip = attout + (size_t)pos*CCH;
    float v[3]; float sum=0.f, sq=0.f;
    #pragma unroll
    for(int k=0;k<3;k++){ v[k] = bf2f(ip[lane + 64*k]); sum += v[k]; sq += v[k]*v[k]; }
    #pragma unroll
    for(int m=1;m<64;m<<=1){ sum += __shfl_xor(sum,m); sq += __shfl_xor(sq,m); }
    float mean = sum*(1.f/192.f);
    float var  = sq*(1.f/192.f) - mean*mean;
    float rstd = rsqrtf(var + 1e-6f);
    uint16_t* op = x2 + (size_t)pos*CCH;
    #pragma unroll
    for(int k=0;k<3;k++){
        int c = lane + 64*k;
        op[c] = f2bf((v[k]-mean)*rstd*g[c] + b[c]);
    }
}

// ---------- kernel 7: cross-att scores + both softmaxes; block per (b, x=w), 512 thr ----------
__global__ __launch_bounds__(512) void k_cross1(const uint16_t* __restrict__ QL,
        const uint16_t* __restrict__ QR, uint16_t* __restrict__ Prow, uint16_t* __restrict__ PcolT){
    __shared__ float S[128*128];  // 64 KB
    __shared__ float cred[4][128];
    __shared__ float colm[128];
    __shared__ float colinv[128];
    int bid = blockIdx.x; int b = bid >> 7, x = bid & 127;
    int tid = threadIdx.x;
    int wv = tid>>6, lane = tid&63, lr = lane&15, lg = lane>>4;   // wv 0..7
    const uint16_t* Abase = QL + (size_t)b*HWSZ*CCH;
    const uint16_t* Bbase = QR + (size_t)b*HWSZ*CCH;
    f32x4 acc[8] = {};
    for(int kk=0; kk<6; kk++){
        int i = wv*16 + lr;
        bf16x8 af = *(const bf16x8*)(Abase + (size_t)(i*WWD + x)*CCH + kk*32 + lg*8);
        #pragma unroll
        for(int nf=0; nf<8; nf++){
            int j = nf*16 + lr;
            bf16x8 bfr = *(const bf16x8*)(Bbase + (size_t)(j*WWD + x)*CCH + kk*32 + lg*8);
            acc[nf] = __builtin_amdgcn_mfma_f32_16x16x32_bf16(af, bfr, acc[nf], 0,0,0);
        }
    }
    #pragma unroll
    for(int nf=0;nf<8;nf++)
    #pragma unroll
    for(int r=0;r<4;r++){
        int i = wv*16 + lg*4 + r; int j = nf*16 + lr;
        S[i*128 + j] = acc[nf][r]*SCALE_F;
    }
    __syncthreads();
    uint16_t* prb = Prow + (size_t)(b*128 + x)*128*128;
    for(int i = wv*16; i < wv*16+16; i++){
        float v0 = S[i*128 + lane], v1 = S[i*128 + 64 + lane];
        float m = fmaxf(v0,v1);
        #pragma unroll
        for(int k=1;k<64;k<<=1) m = fmaxf(m, __shfl_xor(m,k));
        float e0 = __expf(v0-m), e1 = __expf(v1-m);
        float ss = e0+e1;
        #pragma unroll
        for(int k=1;k<64;k<<=1) ss += __shfl_xor(ss,k);
        float inv = 1.f/ss;
        prb[i*128 + lane]      = f2bf(e0*inv);
        prb[i*128 + 64 + lane] = f2bf(e1*inv);
    }
    int j = tid & 127, q4 = tid >> 7;
    int i0 = q4*32;
    float m = -1e30f;
    for(int i=i0; i<i0+32; i++) m = fmaxf(m, S[i*128 + j]);
    cred[q4][j] = m;
    __syncthreads();
    if(tid < 128) colm[tid] = fmaxf(fmaxf(cred[0][tid], cred[1][tid]), fmaxf(cred[2][tid], cred[3][tid]));
    __syncthreads();
    float mj = colm[j];
    float ssum = 0.f;
    for(int i=i0; i<i0+32; i++) ssum += __expf(S[i*128 + j] - mj);
    cred[q4][j] = ssum;
    __syncthreads();
    if(tid < 128) colinv[tid] = 1.f/(cred[0][tid] + cred[1][tid] + cred[2][tid] + cred[3][tid]);
    __syncthreads();
    float cinv = colinv[j];
    uint16_t* pcb = PcolT + (size_t)(b*128 + x)*128*128;
    for(int i=i0; i<i0+32; i++) pcb[j*128 + i] = f2bf(__expf(S[i*128 + j] - mj)*cinv);
}

// ---------- kernel 8: PV GEMMs + residual epilogue -> d_out (512 thr) ----------
__global__ __launch_bounds__(512) void k_cross2(const uint16_t* __restrict__ Prow,
        const uint16_t* __restrict__ PcolT, const uint16_t* __restrict__ VR,
        const uint16_t* __restrict__ VL, const uint16_t* __restrict__ nlr_bf,
        const float* __restrict__ beta, const float* __restrict__ gamma, float* __restrict__ out){
    __shared__ uint16_t VT[192*136];   // 52224 B, reused for VR^T then VL^T
    int bid = blockIdx.x; int b = bid>>7, x = bid&127;
    int tid = threadIdx.x;
    int wv = tid>>6, lane = tid&63, lr = lane&15, lg = lane>>4;   // wv 0..7
    const uint16_t* vrs = VR + (size_t)(b*HWSZ + x*WWD)*CCH;
    const uint16_t* vls = VL + (size_t)(b*HWSZ + x*WWD)*CCH;
    const uint16_t* pr = Prow  + (size_t)(b*128+x)*128*128;
    const uint16_t* pc = PcolT + (size_t)(b*128+x)*128*128;

    for(int idx = tid; idx < 128*24; idx += 512){
        int j = idx / 24, cb = idx % 24;
        uint4 d = *(const uint4*)(vrs + j*CCH + cb*8);
        const uint16_t* dd = (const uint16_t*)&d;
        #pragma unroll
        for(int k=0;k<8;k++) VT[(cb*8+k)*136 + j] = dd[k];
    }
    __syncthreads();
    {
        f32x4 acc[12] = {};
        for(int kk=0; kk<4; kk++){
            int i = wv*16 + lr;
            bf16x8 af = *(const bf16x8*)(pr + i*128 + kk*32 + lg*8);
            #pragma unroll
            for(int nf=0; nf<12; nf++){
                bf16x8 bfr = *(const bf16x8*)(VT + (nf*16+lr)*136 + kk*32 + lg*8);
                acc[nf] = __builtin_amdgcn_mfma_f32_16x16x32_bf16(af, bfr, acc[nf], 0,0,0);
            }
        }
        #pragma unroll
        for(int nf=0; nf<12; nf++){
            int c = nf*16 + lr;
            float bv = beta[c];
            int i0 = wv*16 + lg*4;
            size_t o = ((size_t)(b*CCH + c)*128 + x)*128 + i0;
            const uint16_t* nb = nlr_bf + ((size_t)(b*HWSZ + x*WWD + i0))*CCH + c;
            float4 ov;
            ov.x = bf2f(nb[0*CCH]) + acc[nf][0]*bv;
            ov.y = bf2f(nb[1*CCH]) + acc[nf][1]*bv;
            ov.z = bf2f(nb[2*CCH]) + acc[nf][2]*bv;
            ov.w = bf2f(nb[3*CCH]) + acc[nf][3]*bv;
            *(float4*)(out + o) = ov;
        }
    }
    __syncthreads();
    for(int idx = tid; idx < 128*24; idx += 512){
        int j = idx / 24, cb = idx % 24;
        uint4 d = *(const uint4*)(vls + j*CCH + cb*8);
        const uint16_t* dd = (const uint16_t*)&d;
        #pragma unroll
        for(int k=0;k<8;k++) VT[(cb*8+k)*136 + j] = dd[k];
    }
    __syncthreads();
    {
        f32x4 acc[12] = {};
        for(int kk=0; kk<4; kk++){
            int j = wv*16 + lr;
            bf16x8 af = *(const bf16x8*)(pc + j*128 + kk*32 + lg*8);
            #pragma unroll
            for(int nf=0; nf<12; nf++){
                bf16x8 bfr = *(const bf16x8*)(VT + (nf*16+lr)*136 + kk*32 + lg*8);
                acc[nf] = __builtin_amdgcn_mfma_f32_16x16x32_bf16(af, bfr, acc[nf], 0,0,0);
            }
        }
        float* outr = out + 6291456;
        #pragma unroll
        for(int nf=0; nf<12; nf++){
            int c = nf*16 + lr;
            float gv = gamma[c];
            int j0 = wv*16 + lg*4;
            size_t o = ((size_t)(b*CCH + c)*128 + x)*128 + j0;
            const uint16_t* nb = nlr_bf + ((size_t)(NPOS_SIDE + b*HWSZ + x*WWD + j0))*CCH + c;
            float4 ov;
            ov.x = bf2f(nb[0*CCH]) + acc[nf][0]*gv;
            ov.y = bf2f(nb[1*CCH]) + acc[nf][1]*gv;
            ov.z = bf2f(nb[2*CCH]) + acc[nf][2]*gv;
            ov.w = bf2f(nb[3*CCH]) + acc[nf][3]*gv;
            *(float4*)(outr + o) = ov;
        }
    }
}

// ---------- launch ----------
extern "C" void kernel_launch(void* const* d_in, const int* in_sizes, int n_in,
                              void* d_out, int out_size, void* d_ws, size_t ws_size,
                              hipStream_t stream){
    const float* x_l   = (const float*)d_in[0];
    const float* x_r   = (const float*)d_in[1];
    const float* qkv_w = (const float*)d_in[2];
    const float* qkv_b = (const float*)d_in[3];
    const float* rpb   = (const float*)d_in[4];
    const float* gl    = (const float*)d_in[5];
    const float* bl    = (const float*)d_in[6];
    const float* gr    = (const float*)d_in[7];
    const float* br    = (const float*)d_in[8];
    const float* lp1w  = (const float*)d_in[9];
    const float* lp1b  = (const float*)d_in[10];
    const float* rp1w  = (const float*)d_in[11];
    const float* rp1b  = (const float*)d_in[12];
    const float* lp2w  = (const float*)d_in[13];
    const float* lp2b  = (const float*)d_in[14];
    const float* rp2w  = (const float*)d_in[15];
    const float* rp2b  = (const float*)d_in[16];
    const float* beta  = (const float*)d_in[17];
    const float* gamma = (const float*)d_in[18];
    float* out = (float*)d_out;

    char* ws = (char*)d_ws;
    uint16_t* nlr_bf  = (uint16_t*)(ws + 0);            // 25165824 B
    uint16_t* qkv_bf  = (uint16_t*)(ws + 25165824);     // 75497472 B
    uint16_t* x2      = (uint16_t*)(ws + 25165824);     // alias
    uint16_t* QLb     = (uint16_t*)(ws + 50331648);
    uint16_t* QRb     = (uint16_t*)(ws + 62914560);
    uint16_t* Prow    = (uint16_t*)(ws + 75497472);
    uint16_t* PcolT   = (uint16_t*)(ws + 83886080);
    uint2*    bias_q  = (uint2*)   (ws + 100663296);
    uint16_t* attout  = (uint16_t*)(ws + 102432768);
    uint16_t* VLb     = (uint16_t*)(ws + 102432768);    // alias
    uint16_t* VRb     = (uint16_t*)(ws + 115015680);
    uint16_t* wq      = (uint16_t*)(ws + 127598592);
    uint16_t* w1l     = (uint16_t*)(ws + 127819776);
    uint16_t* w1r     = (uint16_t*)(ws + 127893504);
    uint16_t* w2l     = (uint16_t*)(ws + 127967232);
    uint16_t* w2r     = (uint16_t*)(ws + 128040960);

    k_cvtw<<<dim3(432,5), 256, 0, stream>>>(qkv_w, lp1w, rp1w, lp2w, rp2w, wq, w1l, w1r, w2l, w2r);
    k_bias<<<864, 256, 0, stream>>>(rpb, bias_q);
    k_ln1<<<1024, 256, 0, stream>>>(x_l, x_r, gl, bl, gr, br, nlr_bf);
    k_gemmw<<<dim3(3, 512), 256, 0, stream>>>(nlr_bf, wq, qkv_b, qkv_bf, 192, 576);
    k_attn<<<1536, 256, 0, stream>>>(qkv_bf, bias_q, attout);
    k_ln2<<<16384, 256, 0, stream>>>(attout, gl, bl, gr, br, x2);
    k_gemm4<<<dim3(3, 256, 4), 256, 0, stream>>>(x2, nlr_bf, w1l, w1r, w2l, w2r,
                                                 lp1b, rp1b, lp2b, rp2b, QLb, QRb, VLb, VRb);
    k_cross1<<<256, 512, 0, stream>>>(QLb, QRb, Prow, PcolT);
    k_cross2<<<256, 512, 0, stream>>>(Prow, PcolT, VRb, VLb, nlr_bf, beta, gamma, out);
}